// Round 7
// baseline (12014.524 us; speedup 1.0000x reference)
//
#include <hip/hip_runtime.h>
#include <stdint.h>

// SPINN thin-stack TreeLSTM, MI355X, round 13: ZERO-CROSS-BLOCK full-ownership.
// Theory: r6-r12 all land ~1950us across wildly different pair-sync schemes ->
// the invariant per-step cross-block dependency (agent-scope stores/polls via
// L3/MALL, one visibility latency per step on the A(t)<-B(t-1)<-A(t-2) cycle)
// is the wall; spin rounds show 35-43ms outlier dispatches (pair skew).
// Fix: 128 blocks x 512 thr; block owns batch pair FULLY (128 H, 640 cols,
// K=320). NO inter-block traffic at all. W = 800KB/block, 400 f32/thread in
// 3 tiers: 32 rows regs (f32x2 -> v_pk_fma_f32, halves FMA issue), 12 rows
// LDS (123KB, stride-16B conflict-free), 36 rows streamed from L2 each step
// (same bytes every step -> L2-resident; 368KB/blk/step ~ 3TB/s/XCD < 4.3
// share; 2-deep 4-row chunk pipeline). hrec/crec = plain per-block arrays
// (L1-cached, __syncthreads-ordered; readers are >=2 steps old). Cell = 4
// waves (2 batch x 128 dims, ccprev per-thread); prefetch waves 4-6.
// Deterministic: no atomics, no polls, no tags, no workspace-init assumptions.

#define D     512
#define HD    128
#define LD    64
#define NTHR  512
#define GPR   328   // gpq row stride: 256 quad cols + 64 u cols + pad
#define RREG  32    // W rows/thread in registers
#define RLDS  12    // W rows/thread in LDS
// streamed rows = 80 - RREG - RLDS = 36 (9 chunks x 4)

typedef float f32x2 __attribute__((ext_vector_type(2)));

__device__ __forceinline__ float sigf(float x){ return 1.0f/(1.0f+__expf(-x)); }
__device__ __forceinline__ float tanh_(float x){ return 1.0f-2.0f/(__expf(2.0f*x)+1.0f); }

__global__ __launch_bounds__(NTHR,2) void spinn_kernel(
    const int* __restrict__ trans, const int* __restrict__ labels,
    const float* __restrict__ emb, const float* __restrict__ W,
    const float* __restrict__ bias, const float* __restrict__ leaf,
    float* __restrict__ out, float* __restrict__ hrec_g,
    float* __restrict__ crec_g)
{
  const int bid = blockIdx.x;          // 128 blocks, one batch PAIR each
  const int gb0 = bid*2;
  const int tid = threadIdx.x;
  const int kg = tid>>6, lane = tid&63;
  const int kh = kg>>1, ch = kg&1;     // kh: K-rows [kh*80,+80); ch: col half

  float* hrec = hrec_g + (size_t)bid * ((size_t)D*2*HD);  // intra-block only
  float* crec = crec_g + (size_t)bid * ((size_t)D*2*HD);

  __shared__ __align__(16) float4 lw4[8][RLDS][64];   // LDS W tier (quads)
  __shared__              float  lw1[8][RLDS][64];    // LDS W tier (u col)
  __shared__ __align__(16) float xs[2][2][320];       // [buf][b][k] lab|hl|hr
  __shared__ __align__(16) float gpq[8][2][GPR];      // per-kg gate partials
  __shared__ float bsl[640];                          // bias, global col idx
  __shared__ float lshd[HD];
  __shared__ float clb[2][2][HD];
  __shared__ uint8_t mS[D][2];
  __shared__ short liA[D][2];
  __shared__ unsigned short stk_[2][D];

  // this thread's 5 gate cols: quad base + u col (global col indexing)
  const int gq = (lane>>4)*128 + ch*64 + ((lane*4)&63);
  const int gu = 512 + ch*64 + lane;

  // --- W tier 1: 32 rows in registers as f32x2 pairs (160 f32/thread) ---
  f32x2 wA[RREG], wB[RREG]; float wu[RREG];
#pragma unroll
  for (int j=0;j<RREG;++j){
    const size_t R = (size_t)(kh*80 + j);     // W rows = [lab64|hl128|hr128]
    const float4 w4 = *(const float4*)(W + R*640 + gq);
    f32x2 a; a.x = w4.x; a.y = w4.y; wA[j] = a;
    f32x2 b; b.x = w4.z; b.y = w4.w; wB[j] = b;
    wu[j] = W[R*640 + gu];
  }
  // --- W tier 2: 12 rows in LDS (xs-style stride-16B layout) ---
#pragma unroll
  for (int j=0;j<RLDS;++j){
    const size_t R = (size_t)(kh*80 + RREG + j);
    lw4[kg][j][lane] = *(const float4*)(W + R*640 + gq);
    lw1[kg][j][lane] = W[R*640 + gu];
  }
  for (int c = tid; c < 640; c += NTHR) bsl[c] = bias[c];
  if (tid < HD) lshd[tid] = leaf[tid];
  if (tid < 2){   // precompute (mask, li); ri == t-1 always on a reduce
    int b = tid, p = 0;
    for (int t=0;t<D;++t){
      int m = trans[t*256 + gb0 + b];
      short li = 0;
      if (m) li = (short)stk_[b][p-2];
      mS[t][b] = (uint8_t)m; liA[t][b] = li;
      int np = p - 2*m; stk_[b][np] = (unsigned short)t; p = np+1;
    }
  }
  __syncthreads();

  // --- prefill xs[0]: emb(labels[0]) + leaf (mask(0)==0 by construction) ---
  for (int idx = tid; idx < 640; idx += NTHR){
    const int b = (idx >= 320) ? 1 : 0;
    const int r = idx - b*320;
    xs[0][b][r] = (r < 64) ? emb[(size_t)labels[gb0+b]*LD + r]
                           : lshd[(r-64)&127];
  }
  __syncthreads();

  float ccprev = 0.f;   // own c[t-1][b][h] (cell threads only)

  for (int t=0;t<D;++t){
    const int cur = t&1, nxt = cur^1;

    // ============ P1: GEMM, all 8 waves, zero external dependencies =======
    {
      f32x2 aA0 = {0.f,0.f}, aB0 = {0.f,0.f};
      f32x2 aA1 = {0.f,0.f}, aB1 = {0.f,0.f};
      float u0 = 0.f, u1 = 0.f;
      const float* Wst = W + (size_t)(kh*80 + RREG + RLDS)*640;

      float4 sb4[2][4]; float sb1[2][4];
#pragma unroll
      for (int r=0;r<4;++r){                       // prefetch stream chunk 0
        sb4[0][r] = *(const float4*)(Wst + (size_t)r*640 + gq);
        sb1[0][r] = Wst[(size_t)r*640 + gu];
      }

#define ROW(WAJ,WBJ,WUJ,X0,X1) do{ \
        const f32x2 b0_ = {(X0),(X0)}; const f32x2 b1_ = {(X1),(X1)}; \
        aA0 = __builtin_elementwise_fma((WAJ), b0_, aA0); \
        aB0 = __builtin_elementwise_fma((WBJ), b0_, aB0); \
        u0  = __builtin_fmaf((WUJ), (X0), u0); \
        aA1 = __builtin_elementwise_fma((WAJ), b1_, aA1); \
        aB1 = __builtin_elementwise_fma((WBJ), b1_, aB1); \
        u1  = __builtin_fmaf((WUJ), (X1), u1); } while(0)

      // tier 1: register rows
#pragma unroll
      for (int j4=0;j4<RREG/4;++j4){
        const int k = kh*80 + j4*4;
        const float4 x0 = *(const float4*)&xs[cur][0][k];   // broadcast
        const float4 x1 = *(const float4*)&xs[cur][1][k];
        ROW(wA[j4*4+0],wB[j4*4+0],wu[j4*4+0], x0.x, x1.x);
        ROW(wA[j4*4+1],wB[j4*4+1],wu[j4*4+1], x0.y, x1.y);
        ROW(wA[j4*4+2],wB[j4*4+2],wu[j4*4+2], x0.z, x1.z);
        ROW(wA[j4*4+3],wB[j4*4+3],wu[j4*4+3], x0.w, x1.w);
      }
      // tier 2: LDS rows
#pragma unroll
      for (int j4=0;j4<RLDS/4;++j4){
        const int k = kh*80 + RREG + j4*4;
        const float4 x0 = *(const float4*)&xs[cur][0][k];
        const float4 x1 = *(const float4*)&xs[cur][1][k];
#pragma unroll
        for (int r=0;r<4;++r){
          const float4 w4 = lw4[kg][j4*4+r][lane];
          const float  wuu = lw1[kg][j4*4+r][lane];
          const float xa0 = (r==0)?x0.x:(r==1)?x0.y:(r==2)?x0.z:x0.w;
          const float xa1 = (r==0)?x1.x:(r==1)?x1.y:(r==2)?x1.z:x1.w;
          f32x2 ta; ta.x = w4.x; ta.y = w4.y;
          f32x2 tb; tb.x = w4.z; tb.y = w4.w;
          ROW(ta, tb, wuu, xa0, xa1);
        }
      }
      // tier 3: streamed rows (L2-resident W), 9 chunks x 4, 2-deep pipeline
#pragma unroll
      for (int c=0;c<9;++c){
        if (c+1 < 9){
#pragma unroll
          for (int r=0;r<4;++r){
            sb4[(c+1)&1][r] = *(const float4*)(Wst + (size_t)((c+1)*4+r)*640 + gq);
            sb1[(c+1)&1][r] = Wst[(size_t)((c+1)*4+r)*640 + gu];
          }
        }
        const int k = kh*80 + RREG + RLDS + c*4;
        const float4 x0 = *(const float4*)&xs[cur][0][k];
        const float4 x1 = *(const float4*)&xs[cur][1][k];
#pragma unroll
        for (int r=0;r<4;++r){
          const float4 w4 = sb4[c&1][r];
          const float wuu = sb1[c&1][r];
          const float xa0 = (r==0)?x0.x:(r==1)?x0.y:(r==2)?x0.z:x0.w;
          const float xa1 = (r==0)?x1.x:(r==1)?x1.y:(r==2)?x1.z:x1.w;
          f32x2 ta; ta.x = w4.x; ta.y = w4.y;
          f32x2 tb; tb.x = w4.z; tb.y = w4.w;
          ROW(ta, tb, wuu, xa0, xa1);
        }
      }
#undef ROW
      float4 o0; o0.x = aA0.x; o0.y = aA0.y; o0.z = aB0.x; o0.w = aB0.y;
      float4 o1; o1.x = aA1.x; o1.y = aA1.y; o1.z = aB1.x; o1.w = aB1.y;
      *(float4*)&gpq[kg][0][lane*4] = o0;
      *(float4*)&gpq[kg][1][lane*4] = o1;
      gpq[kg][0][256+lane] = u0;
      gpq[kg][1][256+lane] = u1;
    }
    __syncthreads();

    // ============ P2: cell (waves 0-3) || prefetch t+1 (waves 4-6) ========
    if (tid < 256){
      const int b = tid>>7, h = tid&127, dl = h&63, c2 = h>>6;
      const int m = mS[t][b];
      float s[5];
#pragma unroll
      for (int g=0;g<5;++g){
        const int c = (g<4) ? (g*64+dl) : (256+dl);
        float a = bsl[(g<4) ? (g*128+h) : (512+h)];
#pragma unroll
        for (int k2=0;k2<4;++k2) a += gpq[k2*2+c2][b][c];
        s[g] = a;
      }
      const float cl_ = m ? clb[cur][b][h] : lshd[h];
      const float cr_ = m ? ccprev : lshd[h];   // ri == t-1: own prev c
      const float cc = sigf(s[0])*tanh_(s[4]) + sigf(s[1])*cl_ + sigf(s[2])*cr_;
      const float hh = sigf(s[3])*tanh_(cc);
      ccprev = cc;
      hrec[((size_t)t*2 + b)*HD + h] = hh;      // plain, intra-block only
      crec[((size_t)t*2 + b)*HD + h] = cc;
      if (t == D-1){
        out[(size_t)(gb0+b)*HD + h] = cc;
        out[(size_t)256*HD + (size_t)(gb0+b)*HD + h] = hh;
      } else {
        xs[nxt][b][192+h] = mS[t+1][b] ? hh : lshd[h];   // hr for t+1
      }
      if (t+2 < D && mS[t+2][b] && liA[t+2][b] == t){
        xs[cur][b][64+h] = hh;    // hl for t+2 (li==t case)
        clb[cur][b][h]   = cc;    // cl for t+2
      }
    } else if (kg == 4){          // emb(t+1) -> label slots
      if (t+1 < D){
        const int b = lane>>5, jj = lane&31;
        const int row = labels[(t+1)*256 + gb0 + b];
        const float2 ev = *(const float2*)(emb + (size_t)row*LD + jj*2);
        xs[nxt][b][jj*2]   = ev.x;
        xs[nxt][b][jj*2+1] = ev.y;
      }
    } else if (kg == 5 || kg == 6){  // hl + cl for t+1, b = kg-5
      if (t+1 < D){
        const int b = kg-5;
        const int m1 = mS[t+1][b]; const int li = liA[t+1][b];
        const int h2 = lane*2;
        if (m1){
          if (li <= t-2){           // plain L1-cached reads, barrier-ordered
            const float2 hv = *(const float2*)(hrec + ((size_t)li*2 + b)*HD + h2);
            const float2 cv = *(const float2*)(crec + ((size_t)li*2 + b)*HD + h2);
            xs[nxt][b][64+h2]   = hv.x; xs[nxt][b][64+h2+1] = hv.y;
            clb[nxt][b][h2]     = cv.x; clb[nxt][b][h2+1]   = cv.y;
          }
          // li == t-1: cell@t-1 already wrote xs/clb from registers
        } else {
          xs[nxt][b][64+h2]   = lshd[h2]; xs[nxt][b][64+h2+1] = lshd[h2+1];
          clb[nxt][b][h2]     = lshd[h2]; clb[nxt][b][h2+1]   = lshd[h2+1];
        }
      }
    }
    __syncthreads();
  }
}

extern "C" void kernel_launch(void* const* d_in, const int* in_sizes, int n_in,
                              void* d_out, int out_size, void* d_ws, size_t ws_size,
                              hipStream_t stream) {
  (void)in_sizes; (void)n_in; (void)out_size; (void)ws_size;
  const int*   trans  = (const int*)d_in[0];
  const int*   labels = (const int*)d_in[1];
  const float* emb    = (const float*)d_in[2];
  const float* W      = (const float*)d_in[3];
  const float* bias   = (const float*)d_in[4];
  const float* leaf   = (const float*)d_in[5];
  float* out = (float*)d_out;

  // ws: [0,32MB)   hrec: per-block h records (128 blk x 512 x 2 x 128 f32)
  //     [64MB,96MB) crec: per-block c records
  // No init required: every read (li <= t-2) is write-before-read within the
  // same block, ordered by __syncthreads. No cross-block accesses anywhere.
  uint8_t* ws = (uint8_t*)d_ws;
  float* hrec = (float*)ws;
  float* crec = (float*)(ws + ((size_t)64<<20));

  spinn_kernel<<<dim3(128), dim3(NTHR), 0, stream>>>(
      trans, labels, emb, W, bias, leaf, out, hrec, crec);
}

// Round 8
// 1835.592 us; speedup vs baseline: 6.5453x; 6.5453x over previous
//
#include <hip/hip_runtime.h>
#include <stdint.h>

// SPINN thin-stack TreeLSTM, MI355X, round 14: round-8 chassis, ONE variable:
// pair = (bid, bid^8) -> SAME XCD under the verified bid%8 round-robin
// (learn_hip m09), instead of (2g2, 2g2+1) which straddles two XCDs.
// Theory: the ~6500 cy/step P2 stall is cross-XCD visibility of the relaxed
// agent-scope h publish (store must be snooped out of the writer XCD's L2
// through MALL on every poll) — same-XCD pairs cut that to an L2-local RTT.
// r10 touched this but confounded it with an early-poll restructure (and
// regressed with 42ms skew outliers); r8's in-P2 poll structure is the
// stable one (no outliers across dispatches), so it is kept byte-identical.
// Only other delta: poll spins sleepless for the first 4 tries (dependent
// load latency is the backoff), s_sleep(1) afterward.

#define D     512
#define HD    128
#define LD    64
#define NTHR  512
#define GPR   328   // gp row stride (floats): 256 quad cols + 64 u cols + pad

typedef unsigned long long u64t;

__device__ __forceinline__ float sigf(float x){ return 1.0f/(1.0f+__expf(-x)); }
__device__ __forceinline__ float tanh_(float x){ return 1.0f-2.0f/(__expf(2.0f*x)+1.0f); }
__device__ __forceinline__ u64t gld64(const float* p){
  return __hip_atomic_load((const u64t*)p, __ATOMIC_RELAXED, __HIP_MEMORY_SCOPE_AGENT);
}
__device__ __forceinline__ u64t gld64r(const u64t* p){
  return __hip_atomic_load(p, __ATOMIC_RELAXED, __HIP_MEMORY_SCOPE_AGENT);
}
__device__ __forceinline__ void gst32(float* p, float v){
  __hip_atomic_store(p, v, __ATOMIC_RELAXED, __HIP_MEMORY_SCOPE_AGENT);
}
__device__ __forceinline__ void gst64r(u64t* p, u64t v){
  __hip_atomic_store(p, v, __ATOMIC_RELAXED, __HIP_MEMORY_SCOPE_AGENT);
}
__device__ __forceinline__ u64t packw(float v, unsigned tg){
  return ((u64t)tg << 32) | (u64t)__float_as_uint(v);
}
__device__ __forceinline__ float loww(u64t w){
  return __uint_as_float((unsigned)(w & 0xffffffffu));
}

__global__ __launch_bounds__(NTHR,2) void spinn_kernel(
    const int* __restrict__ trans, const int* __restrict__ labels,
    const float* __restrict__ emb, const float* __restrict__ W,
    const float* __restrict__ bias, const float* __restrict__ leaf,
    float* __restrict__ out, u64t* __restrict__ ring,
    float* __restrict__ rec, float* __restrict__ cown)
{
  const int bid = blockIdx.x;
  // SAME-XCD pair: (bid, bid^8). XCD(bid)=bid%8 -> both blocks one XCD.
  const int g2 = ((bid>>4)<<3) | (bid&7);   // bijective pair index [0,128)
  const int sl = (bid>>3)&1, ps = sl^1;
  const int gb0 = g2*2;
  const int tid = threadIdx.x;
  const int kg = tid>>6, lane = tid&63;
  const int cq = lane;

  __shared__ __align__(16) float xs[2][2][320];     // [buf][b][k]: 64 lab|128 hl|128 hr
  __shared__ __align__(16) float gpq[16][GPR];      // [(kg*2+b)][col]
  __shared__ float bsl[320];
  __shared__ float lshd[HD];
  __shared__ float clb[2][2][64];
  __shared__ uint8_t mS[D][2];
  __shared__ short liA[D][2];
  __shared__ unsigned short stk_[2][D];

  // --- W slice into registers: 40 K-rows x (4 quad cols + 1 u col) ---
  float4 wr4[40]; float wr1[40];
  {
    const int gq = (cq>>4)*128 + sl*64 + ((cq*4)&63);  // quad base (gates 0-3)
    const int gu = 512 + sl*64 + cq;                   // u-gate col
#pragma unroll
    for (int j=0;j<40;++j){
      int k = kg*40 + j;
      wr4[j] = *(const float4*)(W + (size_t)k*640 + gq);
      wr1[j] = W[(size_t)k*640 + gu];
    }
  }
  if (tid < 320){
    int c = tid;
    int gc = (c < 256) ? ((c>>6)*128 + sl*64 + (c&63)) : (512 + sl*64 + (c-256));
    bsl[c] = bias[gc];
  }
  if (tid < HD) lshd[tid] = leaf[tid];
  if (tid < 2){   // precompute (mask, li); ri == t-1 always on a reduce
    int b = tid, p = 0;
    for (int t=0;t<D;++t){
      int m = trans[t*256 + gb0 + b];
      short li = 0;
      if (m) li = (short)stk_[b][p-2];
      mS[t][b] = (uint8_t)m; liA[t][b] = li;
      int np = p - 2*m; stk_[b][np] = (unsigned short)t; p = np+1;
    }
  }
  __syncthreads();

  // --- prefill xs[0]: emb(labels[0]) + leaf (mask(0)==0 by construction) ---
  for (int idx = tid; idx < 640; idx += NTHR){
    int b = (idx >= 320) ? 1 : 0;
    int r = idx - b*320;
    if (r < 64){
      int row = labels[gb0 + b];
      xs[0][b][r] = emb[(size_t)row*LD + r];
    } else {
      xs[0][b][r] = lshd[(r-64)&127];
    }
  }
  __syncthreads();

  auto gemm = [&](int cur){
    float4 a0 = {0.f,0.f,0.f,0.f}, a1 = {0.f,0.f,0.f,0.f};
    float u0 = 0.f, u1 = 0.f;
#pragma unroll
    for (int j4=0;j4<10;++j4){
      int k = kg*40 + j4*4;
      float4 x0 = *(const float4*)&xs[cur][0][k];   // broadcast (all lanes same)
      float4 x1 = *(const float4*)&xs[cur][1][k];
      float xa0[4] = {x0.x,x0.y,x0.z,x0.w};
      float xa1[4] = {x1.x,x1.y,x1.z,x1.w};
#pragma unroll
      for (int jj=0;jj<4;++jj){
        float4 w = wr4[j4*4+jj];
        float wu = wr1[j4*4+jj];
        a0.x = __builtin_fmaf(w.x, xa0[jj], a0.x);
        a0.y = __builtin_fmaf(w.y, xa0[jj], a0.y);
        a0.z = __builtin_fmaf(w.z, xa0[jj], a0.z);
        a0.w = __builtin_fmaf(w.w, xa0[jj], a0.w);
        a1.x = __builtin_fmaf(w.x, xa1[jj], a1.x);
        a1.y = __builtin_fmaf(w.y, xa1[jj], a1.y);
        a1.z = __builtin_fmaf(w.z, xa1[jj], a1.z);
        a1.w = __builtin_fmaf(w.w, xa1[jj], a1.w);
        u0 = __builtin_fmaf(wu, xa0[jj], u0);
        u1 = __builtin_fmaf(wu, xa1[jj], u1);
      }
    }
    *(float4*)&gpq[kg*2+0][cq*4] = a0;
    *(float4*)&gpq[kg*2+1][cq*4] = a1;
    gpq[kg*2+0][256+cq] = u0;
    gpq[kg*2+1][256+cq] = u1;
  };

  float ccprev = 0.f;   // own c[t-1][b][dl] (cell threads only)

  for (int t=0;t<D;++t){
    const int cur = t&1, nxt = cur^1;

    // ---- P1: ALL 8 waves GEMM the full K=320 (xs[cur] complete) ----
    gemm(cur);
    __syncthreads();

    // ---- P2: cell (waves 0-1) || prefetch t+1 (2,3,6) || exchange (7) ----
    if (tid < 128){
      const int b = tid>>6, dl = tid&63, gd = sl*64+dl;
      const int m = mS[t][b];
      float s[5];
#pragma unroll
      for (int g=0; g<5; ++g){
        int c = (g<4) ? (g*64+dl) : (256+dl);
        float a = 0.f;
#pragma unroll
        for (int kk=0; kk<8; ++kk) a += gpq[kk*2+b][c];
        s[g] = a + bsl[c];
      }
      float cl_ = m ? clb[cur][b][dl] : lshd[gd];
      float cr_ = m ? ccprev : lshd[gd];            // ri == t-1: own prev c
      float cc = sigf(s[0])*tanh_(s[4]) + sigf(s[1])*cl_ + sigf(s[2])*cr_;
      float hh = sigf(s[3])*tanh_(cc);
      ccprev = cc;
      // publish self-tagged h FIRST (partner polls it at its P2(t))
      gst64r(ring + (((size_t)(t&7)*128 + g2)*2 + sl)*128 + tid,
             packw(hh, (unsigned)(t+1)));
      size_t ro = (((size_t)t*128 + g2)*2 + sl)*128 + b*64 + dl;
      gst32(rec + ro, hh);
      gst32(cown + ro, cc);
      if (t == D-1){
        out[(size_t)(gb0+b)*HD + gd] = cc;
        out[(size_t)256*HD + (size_t)(gb0+b)*HD + gd] = hh;
      } else {
        xs[nxt][b][192+gd] = mS[t+1][b] ? hh : lshd[gd];   // own hr for t+1
      }
      if (t+2 < D && mS[t+2][b] && liA[t+2][b] == t){
        xs[cur][b][64+gd]  = hh;    // own hl for t+2 (li==t case)
        clb[cur][b][dl]    = cc;    // own cl for t+2
      }
    } else if (kg == 2){            // emb(t+1)
      if (t+1 < D){
        int b = lane>>5, jj = lane&31;
        int row = labels[(t+1)*256 + gb0 + b];
        float2 ev = *(const float2*)(emb + (size_t)row*LD + jj*2);
        xs[nxt][b][jj*2]   = ev.x;
        xs[nxt][b][jj*2+1] = ev.y;
      }
    } else if (kg == 3){            // own-slice hl/cl for t+1
      if (t+1 < D){
        int b = lane>>5, jj = lane&31;
        int m1 = mS[t+1][b]; int li = liA[t+1][b];
        if (m1){
          if (li <= t-2){
            size_t ro = (((size_t)li*128+g2)*2 + sl)*128 + b*64 + jj*2;
            union{u64t u; float f[2];} h_, c_;
            h_.u = gld64(rec + ro);
            c_.u = gld64(cown + ro);
            xs[nxt][b][64+sl*64+jj*2]   = h_.f[0];
            xs[nxt][b][64+sl*64+jj*2+1] = h_.f[1];
            clb[nxt][b][jj*2]   = c_.f[0];
            clb[nxt][b][jj*2+1] = c_.f[1];
          }
          // li == t-1: cell@t-1 already wrote xs/clb from registers
        } else {
          xs[nxt][b][64+sl*64+jj*2]   = lshd[sl*64+jj*2];
          xs[nxt][b][64+sl*64+jj*2+1] = lshd[sl*64+jj*2+1];
          clb[nxt][b][jj*2]   = lshd[sl*64+jj*2];
          clb[nxt][b][jj*2+1] = lshd[sl*64+jj*2+1];
        }
      }
    } else if (kg == 6){            // partner-slice hl for t+1
      if (t+1 < D){
        int b = lane>>5, jj = lane&31;
        int m1 = mS[t+1][b]; int li = liA[t+1][b];
        if (m1){
          if (li <= t-2){
            size_t ro = (((size_t)li*128+g2)*2 + ps)*128 + b*64 + jj*2;
            union{u64t u; float f[2];} h_;
            h_.u = gld64(rec + ro);
            xs[nxt][b][64+ps*64+jj*2]   = h_.f[0];
            xs[nxt][b][64+ps*64+jj*2+1] = h_.f[1];
          } else {                  // li == t-1: ring slot confirmed at P2(t-1)
            const u64t* rp = ring + (((size_t)((t-1)&7)*128 + g2)*2 + ps)*128
                             + b*64 + jj*2;
            xs[nxt][b][64+ps*64+jj*2]   = loww(gld64r(rp));
            xs[nxt][b][64+ps*64+jj*2+1] = loww(gld64r(rp+1));
          }
        } else {
          xs[nxt][b][64+ps*64+jj*2]   = lshd[ps*64+jj*2];
          xs[nxt][b][64+ps*64+jj*2+1] = lshd[ps*64+jj*2+1];
        }
      }
    } else if (kg == 7){            // poll partner h(t); deposit hr for t+1
      if (t+1 < D){
        const u64t* rp = ring + (((size_t)(t&7)*128 + g2)*2 + ps)*128 + lane*2;
        const unsigned want = (unsigned)(t+1);
        u64t w0 = 0, w1 = 0; int it = 0;
        for (;;){
          w0 = gld64r(rp); w1 = gld64r(rp+1);
          int ok = ((unsigned)(w0>>32) == want) & ((unsigned)(w1>>32) == want);
          if (__all(ok)) break;
          if (it >= 4) __builtin_amdgcn_s_sleep(1);   // sleepless first tries
          if (++it > (1<<20)) break;   // safety: hang -> wrong answer
        }
        int b = lane>>5, jj = lane&31;
        if (mS[t+1][b]){
          xs[nxt][b][192+ps*64+jj*2]   = loww(w0);
          xs[nxt][b][192+ps*64+jj*2+1] = loww(w1);
        } else {
          xs[nxt][b][192+ps*64+jj*2]   = lshd[ps*64+jj*2];
          xs[nxt][b][192+ps*64+jj*2+1] = lshd[ps*64+jj*2+1];
        }
      }
    }
    __syncthreads();
  }
}

extern "C" void kernel_launch(void* const* d_in, const int* in_sizes, int n_in,
                              void* d_out, int out_size, void* d_ws, size_t ws_size,
                              hipStream_t stream) {
  (void)in_sizes; (void)n_in; (void)out_size; (void)ws_size;
  const int*   trans  = (const int*)d_in[0];
  const int*   labels = (const int*)d_in[1];
  const float* emb    = (const float*)d_in[2];
  const float* W      = (const float*)d_in[3];
  const float* bias   = (const float*)d_in[4];
  const float* leaf   = (const float*)d_in[5];
  float* out = (float*)d_out;

  // ws: [0, 2MB)   ring: 8-deep self-tagged h records, u64 per (slot,g2,sl,b,dl)
  //               (tag = t+1: 0xAA poison AND zero-init != any live tag;
  //                slot reuse distance 8 steps, pair skew <=1 step -> safe)
  //     [8MB,72MB)  rec:  plain h records (li<=t-2 readers, >=2 steps old)
  //     [72MB,136MB) cown: plain c records (own-block readers only)
  uint8_t* ws = (uint8_t*)d_ws;
  u64t*  ring = (u64t*)ws;
  float* rec  = (float*)(ws + ((size_t)8<<20));
  float* cown = (float*)(ws + ((size_t)72<<20));

  spinn_kernel<<<dim3(256), dim3(NTHR), 0, stream>>>(
      trans, labels, emb, W, bias, leaf, out, ring, rec, cown);
}